// Round 10
// baseline (336.653 us; speedup 1.0000x reference)
//
#include <hip/hip_runtime.h>
#include <hip/hip_bf16.h>

// Problem constants (match reference)
#define N_ATOMS 20000
#define N_EDGES 400000
#define NCH 4
#define F_IN 128
#define S_OUT 32

// ---------- helpers ----------
__device__ __forceinline__ float silu_f(float v) { return v / (1.f + __expf(-v)); }

__device__ __forceinline__ int wave_iscan(int v, int l) {
#pragma unroll
    for (int off = 1; off < 64; off <<= 1) {
        int t = __shfl_up(v, off);
        if (l >= off) v += t;
    }
    return v;
}

// ---------- fill ----------
__global__ void fill_kernel(float* __restrict__ p, int n, float v) {
    int i = blockIdx.x * blockDim.x + threadIdx.x;
    int stride = gridDim.x * blockDim.x;
    for (; i < n; i += stride) p[i] = v;
}

// ---------- CSR build: histogram -> hierarchical scan -> scatter ----------
__global__ void hist_kernel(const int* __restrict__ ei, int* __restrict__ cnt, int E) {
    int e = blockIdx.x * 256 + threadIdx.x;
    if (e < E) atomicAdd(&cnt[ei[E + e]], 1);
}

__global__ __launch_bounds__(256) void scan_l1_kernel(const int* __restrict__ cnt,
                                                      int* __restrict__ rowp,
                                                      int* __restrict__ bsum, int n) {
    int i = blockIdx.x * 256 + threadIdx.x;
    int l = threadIdx.x & 63, w = threadIdx.x >> 6;
    int v = (i < n) ? cnt[i] : 0;
    int incl = wave_iscan(v, l);
    __shared__ int wsum[4];
    if (l == 63) wsum[w] = incl;
    __syncthreads();
    int add = 0;
#pragma unroll
    for (int j = 0; j < 4; ++j) add += (j < w) ? wsum[j] : 0;
    if (i < n) rowp[i] = add + incl - v;
    if (threadIdx.x == 255) bsum[blockIdx.x] = add + incl;
}

__global__ __launch_bounds__(256) void scan_l2_kernel(const int* __restrict__ bsum,
                                                      int* __restrict__ boff,
                                                      int* __restrict__ rowp_n, int nb,
                                                      float* __restrict__ out_zero) {
    int i = threadIdx.x;
    if (i < S_OUT) out_zero[i] = 0.f;  // fused energies zero-init
    int l = i & 63, w = i >> 6;
    int v = (i < nb) ? bsum[i] : 0;
    int incl = wave_iscan(v, l);
    __shared__ int wsum[4];
    if (l == 63) wsum[w] = incl;
    __syncthreads();
    int add = 0;
#pragma unroll
    for (int j = 0; j < 4; ++j) add += (j < w) ? wsum[j] : 0;
    if (i < nb) boff[i] = add + incl - v;
    if (i == nb - 1) *rowp_n = add + incl;
}

__global__ __launch_bounds__(256) void scan_l3_kernel(int* __restrict__ rowp,
                                                      const int* __restrict__ boff, int n) {
    int i = blockIdx.x * 256 + threadIdx.x;
    if (i < n) rowp[i] += boff[blockIdx.x];
}

__global__ void scatter_kernel(const int* __restrict__ ei, const int* __restrict__ rowp,
                               int* __restrict__ fill, int* __restrict__ csr_src, int E) {
    int e = blockIdx.x * 256 + threadIdx.x;
    if (e < E) {
        int d = ei[E + e];
        int pos = rowp[d] + atomicAdd(&fill[d], 1);
        csr_src[pos] = ei[e];
    }
}

// ---------- projection (round-3 LDS structure, b128 + swizzle upgrade) ----------
// block = 32 nodes, c = blockIdx.y. Weights transposed+XOR-swizzled in LDS so each
// lane (=output o) reads 4 weights per ds_read_b128 at even bank spread; inputs
// read as broadcast b128. 9 LDS b128 per 32 wave-FMAs -> VALU-bound. acc[8]/thread.
template <int FIN, bool LN>
__global__ __launch_bounds__(256) void proj_lds_kernel(const float* __restrict__ in,
                                                       const float* __restrict__ gamma,
                                                       const float* __restrict__ beta,
                                                       const float* __restrict__ W,
                                                       const float* __restrict__ a_src,
                                                       const float* __restrict__ a_dst,
                                                       float* __restrict__ out,
                                                       float* __restrict__ es,
                                                       float* __restrict__ ed) {
    constexpr int KQ = FIN / 4;
    constexpr int MASK = (KQ >= 32) ? 31 : 15;
    __shared__ float Wt[64 * FIN];    // [o][swizzled k]
    __shared__ float inl[32 * FIN];   // [node][k]
    const int tid = threadIdx.x;
    const int c = blockIdx.y;
    const int n0 = blockIdx.x * 32;
    const int o = tid & 63;
    const int w = tid >> 6;

    // stage W transposed + swizzled: logical (k,o) -> Wt[o][ ((k>>2)^(o&MASK))*4 + (k&3) ]
    const float* __restrict__ Wc = W + c * (FIN * 64);
    for (int i = tid; i < FIN * 64; i += 256) {
        int k = i >> 6, oo = i & 63;
        Wt[oo * FIN + ((((k >> 2) ^ (oo & MASK)) << 2) | (k & 3))] = Wc[i];
    }
    // stage input rows (raw)
    for (int i = tid; i < 32 * FIN; i += 256) {
        int nl = i / FIN, k = i % FIN;
        inl[i] = in[(size_t)(n0 + nl) * (NCH * FIN) + c * FIN + k];
    }
    __syncthreads();

    if (LN) {  // in-place LayerNorm over each 128-row (wave w owns rows w*8..w*8+7)
        float gl0 = gamma[o], gl1 = gamma[o + 64];
        float bl0 = beta[o], bl1 = beta[o + 64];
#pragma unroll
        for (int r = 0; r < 8; ++r) {
            int row = w * 8 + r;
            float v0 = inl[row * FIN + o], v1 = inl[row * FIN + o + 64];
            float s = v0 + v1, sq = v0 * v0 + v1 * v1;
#pragma unroll
            for (int off = 32; off; off >>= 1) {
                s += __shfl_xor(s, off);
                sq += __shfl_xor(sq, off);
            }
            float mu = s * (1.f / 128.f);
            float rs = rsqrtf(sq * (1.f / 128.f) - mu * mu + 1e-5f);
            inl[row * FIN + o]      = (v0 - mu) * rs * gl0 + bl0;
            inl[row * FIN + o + 64] = (v1 - mu) * rs * gl1 + bl1;
        }
        __syncthreads();
    }

    float asv = a_src[c * 64 + o], adv = a_dst[c * 64 + o];
    float acc[8];
#pragma unroll
    for (int i = 0; i < 8; ++i) acc[i] = 0.f;

#pragma unroll 4
    for (int kq = 0; kq < KQ; ++kq) {
        float4 w4 = *(const float4*)(Wt + o * FIN + ((kq ^ (o & MASK)) << 2));
#pragma unroll
        for (int i = 0; i < 8; ++i) {
            float4 v = *(const float4*)(inl + (w * 8 + i) * FIN + (kq << 2));  // broadcast
            acc[i] = fmaf(v.x, w4.x, fmaf(v.y, w4.y, fmaf(v.z, w4.z, fmaf(v.w, w4.w, acc[i]))));
        }
    }

#pragma unroll
    for (int i = 0; i < 8; ++i) {
        int node = n0 + w * 8 + i;
        out[(size_t)node * 256 + c * 64 + o] = acc[i];
        float vs = acc[i] * asv, vd = acc[i] * adv;
#pragma unroll
        for (int off = 32; off; off >>= 1) {
            vs += __shfl_xor(vs, off);
            vd += __shfl_xor(vd, off);
        }
        if (o == 0) { es[node * NCH + c] = vs; ed[node * NCH + c] = vd; }
    }
}

// ---------- fused GAT aggregation (gather side): softmax + weighted sum ----------
template <bool SILU_OUT>
__global__ __launch_bounds__(256) void gat_gather_kernel(const int* __restrict__ rowp,
                                                         const int* __restrict__ csr_src,
                                                         const float* __restrict__ es,
                                                         const float* __restrict__ ed,
                                                         const float* __restrict__ h,
                                                         float* __restrict__ out) {
    int d = blockIdx.x;
    int c = threadIdx.x >> 6, o = threadIdx.x & 63;
    int r0 = rowp[d], r1 = rowp[d + 1];
    __shared__ int   ssrc[NCH][64];
    __shared__ float sex[NCH][64];
    float edc = ed[d * NCH + c];
    float m = -1e30f, den = 0.f, acc = 0.f;
    for (int base = r0; base < r1; base += 64) {
        int len = min(64, r1 - base);
        float logit = -1e30f;
        int s = 0;
        if (o < len) {
            s = csr_src[base + o];
            float v = es[s * NCH + c] + edc;
            logit = v >= 0.f ? v : 0.2f * v;
        }
        float cm = logit;
#pragma unroll
        for (int off = 32; off; off >>= 1) cm = fmaxf(cm, __shfl_xor(cm, off));
        float nm = fmaxf(m, cm);
        float resc = __expf(m - nm);
        float ex = (o < len) ? __expf(logit - nm) : 0.f;
        float cs = ex;
#pragma unroll
        for (int off = 32; off; off >>= 1) cs += __shfl_xor(cs, off);
        den = den * resc + cs;
        acc *= resc;
        m = nm;
        ssrc[c][o] = s;
        sex[c][o] = ex;
        __syncthreads();
        for (int jj = 0; jj < len; ++jj) {
            int sj = ssrc[c][jj];
            acc += sex[c][jj] * h[(size_t)sj * 256 + c * 64 + o];
        }
        __syncthreads();
    }
    float r = acc / (den + 1e-16f);
    out[(size_t)d * 256 + c * 64 + o] = SILU_OUT ? silu_f(r) : r;
}

// ---------- MLP (64->64->32->1) per channel, LDS weights + b128/swizzle ----------
// c = blockIdx.y; per-channel partial energies accumulate via atomics (linear).
__global__ __launch_bounds__(256) void mlp_lds_kernel(const float* __restrict__ in,
                                                      const float* __restrict__ W1,
                                                      const float* __restrict__ W2,
                                                      const float* __restrict__ W3,
                                                      const int* __restrict__ bat,
                                                      float* __restrict__ out) {
    __shared__ float W1t[64 * 64];   // [o][swz k]
    __shared__ float W2t[32 * 64];   // [o2][swz k]
    __shared__ float w3l[32];
    __shared__ float inl[32 * 64];
    __shared__ float t1l[32 * 64];
    __shared__ float ynode[32];
    const int tid = threadIdx.x;
    const int c = blockIdx.y;
    const int n0 = blockIdx.x * 32;
    const int o = tid & 63;
    const int w = tid >> 6;

    for (int i = tid; i < 4096; i += 256) {
        int k = i >> 6, oo = i & 63;
        W1t[oo * 64 + ((((k >> 2) ^ (oo & 15)) << 2) | (k & 3))] = W1[c * 4096 + i];
    }
    for (int i = tid; i < 2048; i += 256) {
        int k = i >> 5, oo = i & 31;
        W2t[oo * 64 + ((((k >> 2) ^ (oo & 15)) << 2) | (k & 3))] = W2[c * 2048 + i];
    }
    if (tid < 32) w3l[tid] = W3[c * 32 + tid];
    for (int i = tid; i < 2048; i += 256) {
        int nl = i >> 6, k = i & 63;
        inl[i] = in[(size_t)(n0 + nl) * 256 + c * 64 + k];  // already silu'd
    }
    __syncthreads();

    // layer 1: lane = output o, wave covers 8 nodes
    float acc[8];
#pragma unroll
    for (int i = 0; i < 8; ++i) acc[i] = 0.f;
#pragma unroll 4
    for (int kq = 0; kq < 16; ++kq) {
        float4 w4 = *(const float4*)(W1t + o * 64 + ((kq ^ (o & 15)) << 2));
#pragma unroll
        for (int i = 0; i < 8; ++i) {
            float4 v = *(const float4*)(inl + (w * 8 + i) * 64 + (kq << 2));
            acc[i] = fmaf(v.x, w4.x, fmaf(v.y, w4.y, fmaf(v.z, w4.z, fmaf(v.w, w4.w, acc[i]))));
        }
    }
#pragma unroll
    for (int i = 0; i < 8; ++i) t1l[(w * 8 + i) * 64 + o] = silu_f(acc[i]);
    __syncthreads();

    // layers 2+3: half-wave per node
    int hh = o >> 5, o2 = o & 31;
#pragma unroll
    for (int it = 0; it < 4; ++it) {
        int nl = w * 8 + it * 2 + hh;
        float a2 = 0.f;
#pragma unroll 4
        for (int kq = 0; kq < 16; ++kq) {
            float4 w4 = *(const float4*)(W2t + o2 * 64 + ((kq ^ (o2 & 15)) << 2));
            float4 v = *(const float4*)(t1l + nl * 64 + (kq << 2));
            a2 = fmaf(v.x, w4.x, fmaf(v.y, w4.y, fmaf(v.z, w4.z, fmaf(v.w, w4.w, a2))));
        }
        float t = silu_f(a2) * w3l[o2];
#pragma unroll
        for (int off = 16; off; off >>= 1) t += __shfl_xor(t, off);
        if (o2 == 0) ynode[nl] = t;  // each (w,it,hh) owns distinct nl
    }
    __syncthreads();

    // energies: batch-uniform fast path (batch_ids sorted)
    if (tid < 64) {
        int l = tid & 63;
        int n = n0 + (l & 31);
        float val = (l < 32) ? ynode[l] * 0.025f : 0.f;  // /sqrt(4)/20
        int b = bat[n];
        int b0 = __shfl(b, 0);
        if (__all(b == b0)) {
            float t = val;
#pragma unroll
            for (int off = 32; off; off >>= 1) t += __shfl_xor(t, off);
            if (l == 0) atomicAdd(out + b0, t);
        } else if (l < 32) {
            atomicAdd(out + b, val);
        }
    }
}

extern "C" void kernel_launch(void* const* d_in, const int* in_sizes, int n_in,
                              void* d_out, int out_size, void* d_ws, size_t ws_size,
                              hipStream_t stream) {
    const float* x     = (const float*)d_in[0];
    const int*   ei    = (const int*)d_in[1];
    const int*   bat   = (const int*)d_in[2];
    const float* gamma = (const float*)d_in[3];
    const float* beta  = (const float*)d_in[4];
    const float* Wc1   = (const float*)d_in[5];
    const float* as1   = (const float*)d_in[6];
    const float* ad1   = (const float*)d_in[7];
    const float* Wc2   = (const float*)d_in[8];
    const float* as2   = (const float*)d_in[9];
    const float* ad2   = (const float*)d_in[10];
    const float* Wn1   = (const float*)d_in[11];
    const float* Wn2   = (const float*)d_in[12];
    const float* Wout  = (const float*)d_in[13];
    float* out = (float*)d_out;

    // workspace layout (floats)
    float* A    = (float*)d_ws;            // conv outs
    float* B    = A + 10240000;            // proj output h [N,C,64]
    float* es   = B + 5120000;             // 80k
    float* ed   = es + 80000;              // 80k
    int* rowp   = (int*)(ed + 80000);      // 20001 (pad 20004)
    int* cnt    = rowp + 20004;            // 20000
    int* fillc  = cnt + 20000;             // 20000
    int* csr    = fillc + 20000;           // 400000
    int* bsum   = csr + 400000;            // 128
    int* boff   = bsum + 128;              // 128
    float* C1   = A;                       // conv1 out (silu'd) [N,C,64]
    float* C2   = A + 5120000;             // conv2 out (silu'd) [N,C,64]

    dim3 blk(256);
    const int NB = (N_ATOMS + 255) / 256;   // 79
    const int NT = N_ATOMS / 32;            // 625 (exact)

    // ---- CSR build (graph is shared by both convs) ----
    fill_kernel<<<80, blk, 0, stream>>>((float*)cnt, 40000, 0.f);  // cnt + fillc (adjacent)
    hist_kernel<<<(N_EDGES + 255) / 256, blk, 0, stream>>>(ei, cnt, N_EDGES);
    scan_l1_kernel<<<NB, blk, 0, stream>>>(cnt, rowp, bsum, N_ATOMS);
    scan_l2_kernel<<<1, blk, 0, stream>>>(bsum, boff, rowp + N_ATOMS, NB, out);
    scan_l3_kernel<<<NB, blk, 0, stream>>>(rowp, boff, N_ATOMS);
    scatter_kernel<<<(N_EDGES + 255) / 256, blk, 0, stream>>>(ei, rowp, fillc, csr, N_EDGES);

    // ---- conv1 (LN fused into proj staging) ----
    proj_lds_kernel<128, true><<<dim3(NT, NCH), blk, 0, stream>>>(x, gamma, beta, Wc1, as1, ad1, B, es, ed);
    gat_gather_kernel<true><<<N_ATOMS, blk, 0, stream>>>(rowp, csr, es, ed, B, C1);  // silu'd

    // ---- conv2 ----
    proj_lds_kernel<64, false><<<dim3(NT, NCH), blk, 0, stream>>>(C1, gamma, beta, Wc2, as2, ad2, B, es, ed);
    gat_gather_kernel<true><<<N_ATOMS, blk, 0, stream>>>(rowp, csr, es, ed, B, C2);  // silu'd

    // ---- MLP head ----
    mlp_lds_kernel<<<dim3(NT, NCH), blk, 0, stream>>>(C2, Wn1, Wn2, Wout, bat, out);
}

// Round 11
// 309.594 us; speedup vs baseline: 1.0874x; 1.0874x over previous
//
#include <hip/hip_runtime.h>
#include <hip/hip_bf16.h>

// Problem constants (match reference)
#define N_ATOMS 20000
#define N_EDGES 400000
#define NCH 4
#define F_IN 128
#define S_OUT 32

// ---------- helpers ----------
__device__ __forceinline__ float silu_f(float v) { return v / (1.f + __expf(-v)); }

__device__ __forceinline__ int wave_iscan(int v, int l) {
#pragma unroll
    for (int off = 1; off < 64; off <<= 1) {
        int t = __shfl_up(v, off);
        if (l >= off) v += t;
    }
    return v;
}

// ---------- fill ----------
__global__ void fill_kernel(float* __restrict__ p, int n, float v) {
    int i = blockIdx.x * blockDim.x + threadIdx.x;
    int stride = gridDim.x * blockDim.x;
    for (; i < n; i += stride) p[i] = v;
}

// ---------- CSR build: histogram -> hierarchical scan -> scatter ----------
__global__ void hist_kernel(const int* __restrict__ ei, int* __restrict__ cnt, int E) {
    int e = blockIdx.x * 256 + threadIdx.x;
    if (e < E) atomicAdd(&cnt[ei[E + e]], 1);
}

__global__ __launch_bounds__(256) void scan_l1_kernel(const int* __restrict__ cnt,
                                                      int* __restrict__ rowp,
                                                      int* __restrict__ bsum, int n) {
    int i = blockIdx.x * 256 + threadIdx.x;
    int l = threadIdx.x & 63, w = threadIdx.x >> 6;
    int v = (i < n) ? cnt[i] : 0;
    int incl = wave_iscan(v, l);
    __shared__ int wsum[4];
    if (l == 63) wsum[w] = incl;
    __syncthreads();
    int add = 0;
#pragma unroll
    for (int j = 0; j < 4; ++j) add += (j < w) ? wsum[j] : 0;
    if (i < n) rowp[i] = add + incl - v;
    if (threadIdx.x == 255) bsum[blockIdx.x] = add + incl;
}

__global__ __launch_bounds__(256) void scan_l2_kernel(const int* __restrict__ bsum,
                                                      int* __restrict__ boff,
                                                      int* __restrict__ rowp_n, int nb,
                                                      float* __restrict__ out_zero) {
    int i = threadIdx.x;
    if (i < S_OUT) out_zero[i] = 0.f;  // fused energies zero-init
    int l = i & 63, w = i >> 6;
    int v = (i < nb) ? bsum[i] : 0;
    int incl = wave_iscan(v, l);
    __shared__ int wsum[4];
    if (l == 63) wsum[w] = incl;
    __syncthreads();
    int add = 0;
#pragma unroll
    for (int j = 0; j < 4; ++j) add += (j < w) ? wsum[j] : 0;
    if (i < nb) boff[i] = add + incl - v;
    if (i == nb - 1) *rowp_n = add + incl;
}

__global__ __launch_bounds__(256) void scan_l3_kernel(int* __restrict__ rowp,
                                                      const int* __restrict__ boff, int n) {
    int i = blockIdx.x * 256 + threadIdx.x;
    if (i < n) rowp[i] += boff[blockIdx.x];
}

__global__ void scatter_kernel(const int* __restrict__ ei, const int* __restrict__ rowp,
                               int* __restrict__ fill, int* __restrict__ csr_src, int E) {
    int e = blockIdx.x * 256 + threadIdx.x;
    if (e < E) {
        int d = ei[E + e];
        int pos = rowp[d] + atomicAdd(&fill[d], 1);
        csr_src[pos] = ei[e];
    }
}

// ---------- projection: 2-node x 4-output register tile ----------
// block = 32 nodes, c = blockIdx.y. thread (np=t>>4, oq=t&15) owns acc[2][4].
// Per kq: 2 input b128 (padded stride, 16-way broadcast, conflict-free) +
// 4 weight b128 ([o][k], kq XOR o>>2 swizzle) -> 32 FMAs. 1 B/FMA from LDS.
template <int FIN, int IN_STRIDE, bool LN>
__global__ __launch_bounds__(256) void proj_kernel(const float* __restrict__ in,
                                                   const float* __restrict__ gamma,
                                                   const float* __restrict__ beta,
                                                   const float* __restrict__ W,
                                                   const float* __restrict__ a_src,
                                                   const float* __restrict__ a_dst,
                                                   float* __restrict__ out,
                                                   float* __restrict__ es,
                                                   float* __restrict__ ed) {
    constexpr int KQ = FIN / 4;
    constexpr int KQM = KQ - 1;
    constexpr int WS = FIN + 4;       // padded input stride (16B-aligned, bank-spread)
    __shared__ float Wt[64 * FIN];    // [o][swizzled k]
    __shared__ float inl[32 * WS];    // [node][k] padded
    const int tid = threadIdx.x;
    const int c = blockIdx.y;
    const int n0 = blockIdx.x * 32;
    const int np = tid >> 4;          // node pair 0..15
    const int oq = tid & 15;          // output quad 0..15

    // stage W transposed+swizzled: (k,o) -> Wt[o*FIN + (((k>>2)^(o>>2))&KQM)*4 + (k&3)]
    const float* __restrict__ Wc = W + c * (FIN * 64);
    for (int i = tid; i < FIN * 64; i += 256) {
        int k = i >> 6, oo = i & 63;
        Wt[oo * FIN + (((((k >> 2) ^ (oo >> 2)) & KQM) << 2) | (k & 3))] = Wc[i];
    }
    // stage input rows
    for (int i = tid; i < 32 * FIN; i += 256) {
        int nl = i / FIN, k = i & (FIN - 1);
        inl[nl * WS + k] = in[(size_t)(n0 + nl) * IN_STRIDE + c * FIN + k];
    }
    __syncthreads();

    if (LN) {  // in-place LayerNorm per 128-row; wave w owns rows 8w..8w+7
        int l = tid & 63, w = tid >> 6;
        float gl0 = gamma[l], gl1 = gamma[l + 64];
        float bl0 = beta[l], bl1 = beta[l + 64];
#pragma unroll
        for (int r = 0; r < 8; ++r) {
            int row = w * 8 + r;
            float v0 = inl[row * WS + l], v1 = inl[row * WS + l + 64];
            float s = v0 + v1, sq = v0 * v0 + v1 * v1;
#pragma unroll
            for (int off = 32; off; off >>= 1) {
                s += __shfl_xor(s, off);
                sq += __shfl_xor(sq, off);
            }
            float mu = s * (1.f / 128.f);
            float rs = rsqrtf(sq * (1.f / 128.f) - mu * mu + 1e-5f);
            inl[row * WS + l]      = (v0 - mu) * rs * gl0 + bl0;
            inl[row * WS + l + 64] = (v1 - mu) * rs * gl1 + bl1;
        }
        __syncthreads();
    }

    float acc[2][4];
#pragma unroll
    for (int i = 0; i < 2; ++i)
#pragma unroll
        for (int j = 0; j < 4; ++j) acc[i][j] = 0.f;

    const float* inp0 = inl + (np * 2) * WS;
    const float* inp1 = inl + (np * 2 + 1) * WS;
    const float* wp = Wt + (oq * 4) * FIN;

#pragma unroll 2
    for (int kq = 0; kq < KQ; ++kq) {
        int skq = ((kq ^ oq) & KQM) << 2;
        float4 v0 = *(const float4*)(inp0 + (kq << 2));
        float4 v1 = *(const float4*)(inp1 + (kq << 2));
        float4 w0 = *(const float4*)(wp + skq);
        float4 w1 = *(const float4*)(wp + FIN + skq);
        float4 w2 = *(const float4*)(wp + 2 * FIN + skq);
        float4 w3 = *(const float4*)(wp + 3 * FIN + skq);
        acc[0][0] = fmaf(v0.x, w0.x, fmaf(v0.y, w0.y, fmaf(v0.z, w0.z, fmaf(v0.w, w0.w, acc[0][0]))));
        acc[0][1] = fmaf(v0.x, w1.x, fmaf(v0.y, w1.y, fmaf(v0.z, w1.z, fmaf(v0.w, w1.w, acc[0][1]))));
        acc[0][2] = fmaf(v0.x, w2.x, fmaf(v0.y, w2.y, fmaf(v0.z, w2.z, fmaf(v0.w, w2.w, acc[0][2]))));
        acc[0][3] = fmaf(v0.x, w3.x, fmaf(v0.y, w3.y, fmaf(v0.z, w3.z, fmaf(v0.w, w3.w, acc[0][3]))));
        acc[1][0] = fmaf(v1.x, w0.x, fmaf(v1.y, w0.y, fmaf(v1.z, w0.z, fmaf(v1.w, w0.w, acc[1][0]))));
        acc[1][1] = fmaf(v1.x, w1.x, fmaf(v1.y, w1.y, fmaf(v1.z, w1.z, fmaf(v1.w, w1.w, acc[1][1]))));
        acc[1][2] = fmaf(v1.x, w2.x, fmaf(v1.y, w2.y, fmaf(v1.z, w2.z, fmaf(v1.w, w2.w, acc[1][2]))));
        acc[1][3] = fmaf(v1.x, w3.x, fmaf(v1.y, w3.y, fmaf(v1.z, w3.z, fmaf(v1.w, w3.w, acc[1][3]))));
    }

    float4 av4 = *(const float4*)(a_src + c * 64 + oq * 4);
    float4 bv4 = *(const float4*)(a_dst + c * 64 + oq * 4);
#pragma unroll
    for (int i = 0; i < 2; ++i) {
        int node = n0 + np * 2 + i;
        *(float4*)(out + (size_t)node * 256 + c * 64 + oq * 4) =
            make_float4(acc[i][0], acc[i][1], acc[i][2], acc[i][3]);
        float ps = acc[i][0] * av4.x + acc[i][1] * av4.y + acc[i][2] * av4.z + acc[i][3] * av4.w;
        float pd = acc[i][0] * bv4.x + acc[i][1] * bv4.y + acc[i][2] * bv4.z + acc[i][3] * bv4.w;
#pragma unroll
        for (int off = 1; off < 16; off <<= 1) {
            ps += __shfl_xor(ps, off);
            pd += __shfl_xor(pd, off);
        }
        if (oq == 0) { es[node * NCH + c] = ps; ed[node * NCH + c] = pd; }
    }
}

// ---------- fused GAT aggregation: wave-autonomous, LDS-free ----------
// wave = (dst, channel); phase A: lane = edge (logit/exp); phase B: lane =
// feature, edge scalars via readlane (__shfl with uniform idx), 4-wide load ILP.
template <bool SILU_OUT>
__global__ __launch_bounds__(256) void gat_gather_kernel(const int* __restrict__ rowp,
                                                         const int* __restrict__ csr_src,
                                                         const float* __restrict__ es,
                                                         const float* __restrict__ ed,
                                                         const float* __restrict__ h,
                                                         float* __restrict__ out) {
    int d = blockIdx.x;
    int c = threadIdx.x >> 6, o = threadIdx.x & 63;
    int r0 = rowp[d], r1 = rowp[d + 1];
    float edc = ed[d * NCH + c];
    float m = -1e30f, den = 0.f, acc = 0.f;
    const float* __restrict__ hc = h + c * 64 + o;
    for (int base = r0; base < r1; base += 64) {
        int len = min(64, r1 - base);
        float logit = -1e30f;
        int s = 0;
        if (o < len) {
            s = csr_src[base + o];
            float v = es[s * NCH + c] + edc;
            logit = v >= 0.f ? v : 0.2f * v;
        }
        float cm = logit;
#pragma unroll
        for (int off = 32; off; off >>= 1) cm = fmaxf(cm, __shfl_xor(cm, off));
        float nm = fmaxf(m, cm);
        float resc = __expf(m - nm);
        float ex = (o < len) ? __expf(logit - nm) : 0.f;
        float cs = ex;
#pragma unroll
        for (int off = 32; off; off >>= 1) cs += __shfl_xor(cs, off);
        den = den * resc + cs;
        acc *= resc;
        m = nm;
        // phase B: 4-wide pipelined gather of h rows
        int jj = 0;
        for (; jj + 4 <= len; jj += 4) {
            int s0 = __shfl(s, jj), s1 = __shfl(s, jj + 1);
            int s2 = __shfl(s, jj + 2), s3 = __shfl(s, jj + 3);
            float e0 = __shfl(ex, jj), e1 = __shfl(ex, jj + 1);
            float e2 = __shfl(ex, jj + 2), e3 = __shfl(ex, jj + 3);
            float h0 = hc[(size_t)s0 * 256];
            float h1 = hc[(size_t)s1 * 256];
            float h2 = hc[(size_t)s2 * 256];
            float h3 = hc[(size_t)s3 * 256];
            acc = fmaf(e0, h0, fmaf(e1, h1, fmaf(e2, h2, fmaf(e3, h3, acc))));
        }
        for (; jj < len; ++jj) {
            int sj = __shfl(s, jj);
            float ej = __shfl(ex, jj);
            acc = fmaf(ej, hc[(size_t)sj * 256], acc);
        }
    }
    float r = acc / (den + 1e-16f);
    out[(size_t)d * 256 + c * 64 + o] = SILU_OUT ? silu_f(r) : r;
}

// ---------- MLP (64->64->32->1) per channel, LDS weights + b128/swizzle ----------
__global__ __launch_bounds__(256) void mlp_lds_kernel(const float* __restrict__ in,
                                                      const float* __restrict__ W1,
                                                      const float* __restrict__ W2,
                                                      const float* __restrict__ W3,
                                                      const int* __restrict__ bat,
                                                      float* __restrict__ out) {
    __shared__ float W1t[64 * 64];   // [o][swz k]
    __shared__ float W2t[32 * 64];   // [o2][swz k]
    __shared__ float w3l[32];
    __shared__ float inl[32 * 64];
    __shared__ float t1l[32 * 64];
    __shared__ float ynode[32];
    const int tid = threadIdx.x;
    const int c = blockIdx.y;
    const int n0 = blockIdx.x * 32;
    const int o = tid & 63;
    const int w = tid >> 6;

    for (int i = tid; i < 4096; i += 256) {
        int k = i >> 6, oo = i & 63;
        W1t[oo * 64 + ((((k >> 2) ^ (oo >> 2)) & 15) << 2 | (k & 3))] = W1[c * 4096 + i];
    }
    for (int i = tid; i < 2048; i += 256) {
        int k = i >> 5, oo = i & 31;
        W2t[oo * 64 + ((((k >> 2) ^ (oo >> 2)) & 15) << 2 | (k & 3))] = W2[c * 2048 + i];
    }
    if (tid < 32) w3l[tid] = W3[c * 32 + tid];
    for (int i = tid; i < 2048; i += 256) {
        int nl = i >> 6, k = i & 63;
        inl[i] = in[(size_t)(n0 + nl) * 256 + c * 64 + k];  // already silu'd
    }
    __syncthreads();

    // layer 1: lane = output o, wave covers 8 nodes
    float acc[8];
#pragma unroll
    for (int i = 0; i < 8; ++i) acc[i] = 0.f;
#pragma unroll 4
    for (int kq = 0; kq < 16; ++kq) {
        float4 w4 = *(const float4*)(W1t + o * 64 + (((kq ^ (o >> 2)) & 15) << 2));
#pragma unroll
        for (int i = 0; i < 8; ++i) {
            float4 v = *(const float4*)(inl + (w * 8 + i) * 64 + (kq << 2));
            acc[i] = fmaf(v.x, w4.x, fmaf(v.y, w4.y, fmaf(v.z, w4.z, fmaf(v.w, w4.w, acc[i]))));
        }
    }
#pragma unroll
    for (int i = 0; i < 8; ++i) t1l[(w * 8 + i) * 64 + o] = silu_f(acc[i]);
    __syncthreads();

    // layers 2+3: half-wave per node
    int hh = o >> 5, o2 = o & 31;
#pragma unroll
    for (int it = 0; it < 4; ++it) {
        int nl = w * 8 + it * 2 + hh;
        float a2 = 0.f;
#pragma unroll 4
        for (int kq = 0; kq < 16; ++kq) {
            float4 w4 = *(const float4*)(W2t + o2 * 64 + (((kq ^ (o2 >> 2)) & 15) << 2));
            float4 v = *(const float4*)(t1l + nl * 64 + (kq << 2));
            a2 = fmaf(v.x, w4.x, fmaf(v.y, w4.y, fmaf(v.z, w4.z, fmaf(v.w, w4.w, a2))));
        }
        float t = silu_f(a2) * w3l[o2];
#pragma unroll
        for (int off = 16; off; off >>= 1) t += __shfl_xor(t, off);
        if (o2 == 0) ynode[nl] = t;
    }
    __syncthreads();

    // energies: batch-uniform fast path (batch_ids sorted)
    if (tid < 64) {
        int l = tid & 63;
        int n = n0 + (l & 31);
        float val = (l < 32) ? ynode[l] * 0.025f : 0.f;  // /sqrt(4)/20
        int b = bat[n];
        int b0 = __shfl(b, 0);
        if (__all(b == b0)) {
            float t = val;
#pragma unroll
            for (int off = 32; off; off >>= 1) t += __shfl_xor(t, off);
            if (l == 0) atomicAdd(out + b0, t);
        } else if (l < 32) {
            atomicAdd(out + b, val);
        }
    }
}

extern "C" void kernel_launch(void* const* d_in, const int* in_sizes, int n_in,
                              void* d_out, int out_size, void* d_ws, size_t ws_size,
                              hipStream_t stream) {
    const float* x     = (const float*)d_in[0];
    const int*   ei    = (const int*)d_in[1];
    const int*   bat   = (const int*)d_in[2];
    const float* gamma = (const float*)d_in[3];
    const float* beta  = (const float*)d_in[4];
    const float* Wc1   = (const float*)d_in[5];
    const float* as1   = (const float*)d_in[6];
    const float* ad1   = (const float*)d_in[7];
    const float* Wc2   = (const float*)d_in[8];
    const float* as2   = (const float*)d_in[9];
    const float* ad2   = (const float*)d_in[10];
    const float* Wn1   = (const float*)d_in[11];
    const float* Wn2   = (const float*)d_in[12];
    const float* Wout  = (const float*)d_in[13];
    float* out = (float*)d_out;

    // workspace layout (floats)
    float* A    = (float*)d_ws;            // conv outs
    float* B    = A + 10240000;            // proj output h [N,C,64]
    float* es   = B + 5120000;             // 80k
    float* ed   = es + 80000;              // 80k
    int* rowp   = (int*)(ed + 80000);      // 20001 (pad 20004)
    int* cnt    = rowp + 20004;            // 20000
    int* fillc  = cnt + 20000;             // 20000
    int* csr    = fillc + 20000;           // 400000
    int* bsum   = csr + 400000;            // 128
    int* boff   = bsum + 128;              // 128
    float* C1   = A;                       // conv1 out (silu'd) [N,C,64]
    float* C2   = A + 5120000;             // conv2 out (silu'd) [N,C,64]

    dim3 blk(256);
    const int NB = (N_ATOMS + 255) / 256;   // 79
    const int NT = N_ATOMS / 32;            // 625 (exact)

    // ---- CSR build (graph is shared by both convs) ----
    fill_kernel<<<80, blk, 0, stream>>>((float*)cnt, 40000, 0.f);  // cnt + fillc (adjacent)
    hist_kernel<<<(N_EDGES + 255) / 256, blk, 0, stream>>>(ei, cnt, N_EDGES);
    scan_l1_kernel<<<NB, blk, 0, stream>>>(cnt, rowp, bsum, N_ATOMS);
    scan_l2_kernel<<<1, blk, 0, stream>>>(bsum, boff, rowp + N_ATOMS, NB, out);
    scan_l3_kernel<<<NB, blk, 0, stream>>>(rowp, boff, N_ATOMS);
    scatter_kernel<<<(N_EDGES + 255) / 256, blk, 0, stream>>>(ei, rowp, fillc, csr, N_EDGES);

    // ---- conv1 (LN fused into proj staging) ----
    proj_kernel<128, NCH * F_IN, true><<<dim3(NT, NCH), blk, 0, stream>>>(x, gamma, beta, Wc1, as1, ad1, B, es, ed);
    gat_gather_kernel<true><<<N_ATOMS, blk, 0, stream>>>(rowp, csr, es, ed, B, C1);  // silu'd

    // ---- conv2 ----
    proj_kernel<64, 256, false><<<dim3(NT, NCH), blk, 0, stream>>>(C1, gamma, beta, Wc2, as2, ad2, B, es, ed);
    gat_gather_kernel<true><<<N_ATOMS, blk, 0, stream>>>(rowp, csr, es, ed, B, C2);  // silu'd

    // ---- MLP head ----
    mlp_lds_kernel<<<dim3(NT, NCH), blk, 0, stream>>>(C2, Wn1, Wn2, Wout, bat, out);
}

// Round 12
// 296.357 us; speedup vs baseline: 1.1360x; 1.0447x over previous
//
#include <hip/hip_runtime.h>
#include <hip/hip_bf16.h>

// Problem constants (match reference)
#define N_ATOMS 20000
#define N_EDGES 400000
#define NCH 4
#define F_IN 128
#define S_OUT 32

// ---------- helpers ----------
__device__ __forceinline__ float silu_f(float v) { return v / (1.f + __expf(-v)); }

__device__ __forceinline__ int wave_iscan(int v, int l) {
#pragma unroll
    for (int off = 1; off < 64; off <<= 1) {
        int t = __shfl_up(v, off);
        if (l >= off) v += t;
    }
    return v;
}

// ---------- fill ----------
__global__ void fill_kernel(float* __restrict__ p, int n, float v) {
    int i = blockIdx.x * blockDim.x + threadIdx.x;
    int stride = gridDim.x * blockDim.x;
    for (; i < n; i += stride) p[i] = v;
}

// ---------- CSR build: histogram -> hierarchical scan -> scatter ----------
__global__ void hist_kernel(const int* __restrict__ ei, int* __restrict__ cnt, int E) {
    int e = blockIdx.x * 256 + threadIdx.x;
    if (e < E) atomicAdd(&cnt[ei[E + e]], 1);
}

__global__ __launch_bounds__(256) void scan_l1_kernel(const int* __restrict__ cnt,
                                                      int* __restrict__ rowp,
                                                      int* __restrict__ bsum, int n) {
    int i = blockIdx.x * 256 + threadIdx.x;
    int l = threadIdx.x & 63, w = threadIdx.x >> 6;
    int v = (i < n) ? cnt[i] : 0;
    int incl = wave_iscan(v, l);
    __shared__ int wsum[4];
    if (l == 63) wsum[w] = incl;
    __syncthreads();
    int add = 0;
#pragma unroll
    for (int j = 0; j < 4; ++j) add += (j < w) ? wsum[j] : 0;
    if (i < n) rowp[i] = add + incl - v;
    if (threadIdx.x == 255) bsum[blockIdx.x] = add + incl;
}

__global__ __launch_bounds__(256) void scan_l2_kernel(const int* __restrict__ bsum,
                                                      int* __restrict__ boff,
                                                      int* __restrict__ rowp_n, int nb,
                                                      float* __restrict__ out_zero) {
    int i = threadIdx.x;
    if (i < S_OUT) out_zero[i] = 0.f;  // fused energies zero-init
    int l = i & 63, w = i >> 6;
    int v = (i < nb) ? bsum[i] : 0;
    int incl = wave_iscan(v, l);
    __shared__ int wsum[4];
    if (l == 63) wsum[w] = incl;
    __syncthreads();
    int add = 0;
#pragma unroll
    for (int j = 0; j < 4; ++j) add += (j < w) ? wsum[j] : 0;
    if (i < nb) boff[i] = add + incl - v;
    if (i == nb - 1) *rowp_n = add + incl;
}

__global__ __launch_bounds__(256) void scan_l3_kernel(int* __restrict__ rowp,
                                                      const int* __restrict__ boff, int n) {
    int i = blockIdx.x * 256 + threadIdx.x;
    if (i < n) rowp[i] += boff[blockIdx.x];
}

__global__ void scatter_kernel(const int* __restrict__ ei, const int* __restrict__ rowp,
                               int* __restrict__ fill, int* __restrict__ csr_src, int E) {
    int e = blockIdx.x * 256 + threadIdx.x;
    if (e < E) {
        int d = ei[E + e];
        int pos = rowp[d] + atomicAdd(&fill[d], 1);
        csr_src[pos] = ei[e];
    }
}

// ---------- projection: 2-node x 4-output register tile ----------
// block = 32 nodes, c = blockIdx.y. thread (np=t>>4, oq=t&15) owns acc[2][4].
// Wt rows padded to FIN+4 (row base advances 4 banks/row -> ~2-way staging writes;
// reads stay <=2-way via (kq^oq) swizzle). inl padded likewise.
template <int FIN, int IN_STRIDE, bool LN, bool ATT, bool SILU_OUT>
__global__ __launch_bounds__(256) void proj_kernel(const float* __restrict__ in,
                                                   const float* __restrict__ gamma,
                                                   const float* __restrict__ beta,
                                                   const float* __restrict__ W,
                                                   const float* __restrict__ a_src,
                                                   const float* __restrict__ a_dst,
                                                   float* __restrict__ out,
                                                   float* __restrict__ es,
                                                   float* __restrict__ ed) {
    constexpr int KQ = FIN / 4;
    constexpr int KQM = KQ - 1;
    constexpr int WS = FIN + 4;       // padded stride (16B-aligned, bank-spread)
    __shared__ float Wt[64 * WS];     // [o][swizzled k], padded
    __shared__ float inl[32 * WS];    // [node][k], padded
    const int tid = threadIdx.x;
    const int c = blockIdx.y;
    const int n0 = blockIdx.x * 32;
    const int np = tid >> 4;          // node pair 0..15
    const int oq = tid & 15;          // output quad 0..15

    // stage W transposed+swizzled: (k,o) -> Wt[o*WS + (((k>>2)^(o>>2))&KQM)*4 + (k&3)]
    const float* __restrict__ Wc = W + c * (FIN * 64);
    for (int i = tid; i < FIN * 64; i += 256) {
        int k = i >> 6, oo = i & 63;
        Wt[oo * WS + (((((k >> 2) ^ (oo >> 2)) & KQM) << 2) | (k & 3))] = Wc[i];
    }
    // stage input rows
    for (int i = tid; i < 32 * FIN; i += 256) {
        int nl = i / FIN, k = i & (FIN - 1);
        inl[nl * WS + k] = in[(size_t)(n0 + nl) * IN_STRIDE + c * FIN + k];
    }
    __syncthreads();

    if (LN) {  // in-place LayerNorm per 128-row; wave w owns rows 8w..8w+7
        int l = tid & 63, w = tid >> 6;
        float gl0 = gamma[l], gl1 = gamma[l + 64];
        float bl0 = beta[l], bl1 = beta[l + 64];
#pragma unroll
        for (int r = 0; r < 8; ++r) {
            int row = w * 8 + r;
            float v0 = inl[row * WS + l], v1 = inl[row * WS + l + 64];
            float s = v0 + v1, sq = v0 * v0 + v1 * v1;
#pragma unroll
            for (int off = 32; off; off >>= 1) {
                s += __shfl_xor(s, off);
                sq += __shfl_xor(sq, off);
            }
            float mu = s * (1.f / 128.f);
            float rs = rsqrtf(sq * (1.f / 128.f) - mu * mu + 1e-5f);
            inl[row * WS + l]      = (v0 - mu) * rs * gl0 + bl0;
            inl[row * WS + l + 64] = (v1 - mu) * rs * gl1 + bl1;
        }
        __syncthreads();
    }

    float acc[2][4];
#pragma unroll
    for (int i = 0; i < 2; ++i)
#pragma unroll
        for (int j = 0; j < 4; ++j) acc[i][j] = 0.f;

    const float* inp0 = inl + (np * 2) * WS;
    const float* inp1 = inl + (np * 2 + 1) * WS;
    const float* wp = Wt + (oq * 4) * WS;

#pragma unroll 2
    for (int kq = 0; kq < KQ; ++kq) {
        int skq = ((kq ^ oq) & KQM) << 2;
        float4 v0 = *(const float4*)(inp0 + (kq << 2));
        float4 v1 = *(const float4*)(inp1 + (kq << 2));
        float4 w0 = *(const float4*)(wp + skq);
        float4 w1 = *(const float4*)(wp + WS + skq);
        float4 w2 = *(const float4*)(wp + 2 * WS + skq);
        float4 w3 = *(const float4*)(wp + 3 * WS + skq);
        acc[0][0] = fmaf(v0.x, w0.x, fmaf(v0.y, w0.y, fmaf(v0.z, w0.z, fmaf(v0.w, w0.w, acc[0][0]))));
        acc[0][1] = fmaf(v0.x, w1.x, fmaf(v0.y, w1.y, fmaf(v0.z, w1.z, fmaf(v0.w, w1.w, acc[0][1]))));
        acc[0][2] = fmaf(v0.x, w2.x, fmaf(v0.y, w2.y, fmaf(v0.z, w2.z, fmaf(v0.w, w2.w, acc[0][2]))));
        acc[0][3] = fmaf(v0.x, w3.x, fmaf(v0.y, w3.y, fmaf(v0.z, w3.z, fmaf(v0.w, w3.w, acc[0][3]))));
        acc[1][0] = fmaf(v1.x, w0.x, fmaf(v1.y, w0.y, fmaf(v1.z, w0.z, fmaf(v1.w, w0.w, acc[1][0]))));
        acc[1][1] = fmaf(v1.x, w1.x, fmaf(v1.y, w1.y, fmaf(v1.z, w1.z, fmaf(v1.w, w1.w, acc[1][1]))));
        acc[1][2] = fmaf(v1.x, w2.x, fmaf(v1.y, w2.y, fmaf(v1.z, w2.z, fmaf(v1.w, w2.w, acc[1][2]))));
        acc[1][3] = fmaf(v1.x, w3.x, fmaf(v1.y, w3.y, fmaf(v1.z, w3.z, fmaf(v1.w, w3.w, acc[1][3]))));
    }

#pragma unroll
    for (int i = 0; i < 2; ++i) {
        int node = n0 + np * 2 + i;
        float4 ov;
        if (SILU_OUT)
            ov = make_float4(silu_f(acc[i][0]), silu_f(acc[i][1]), silu_f(acc[i][2]), silu_f(acc[i][3]));
        else
            ov = make_float4(acc[i][0], acc[i][1], acc[i][2], acc[i][3]);
        *(float4*)(out + (size_t)node * 256 + c * 64 + oq * 4) = ov;
        if (ATT) {
            float4 av4 = *(const float4*)(a_src + c * 64 + oq * 4);
            float4 bv4 = *(const float4*)(a_dst + c * 64 + oq * 4);
            float ps = acc[i][0] * av4.x + acc[i][1] * av4.y + acc[i][2] * av4.z + acc[i][3] * av4.w;
            float pd = acc[i][0] * bv4.x + acc[i][1] * bv4.y + acc[i][2] * bv4.z + acc[i][3] * bv4.w;
#pragma unroll
            for (int off = 1; off < 16; off <<= 1) {
                ps += __shfl_xor(ps, off);
                pd += __shfl_xor(pd, off);
            }
            if (oq == 0) { es[node * NCH + c] = ps; ed[node * NCH + c] = pd; }
        }
    }
}

// ---------- fused GAT aggregation: wave-autonomous, LDS-free ----------
template <bool SILU_OUT>
__global__ __launch_bounds__(256) void gat_gather_kernel(const int* __restrict__ rowp,
                                                         const int* __restrict__ csr_src,
                                                         const float* __restrict__ es,
                                                         const float* __restrict__ ed,
                                                         const float* __restrict__ h,
                                                         float* __restrict__ out) {
    int d = blockIdx.x;
    int c = threadIdx.x >> 6, o = threadIdx.x & 63;
    int r0 = rowp[d], r1 = rowp[d + 1];
    float edc = ed[d * NCH + c];
    float m = -1e30f, den = 0.f, acc = 0.f;
    const float* __restrict__ hc = h + c * 64 + o;
    for (int base = r0; base < r1; base += 64) {
        int len = min(64, r1 - base);
        float logit = -1e30f;
        int s = 0;
        if (o < len) {
            s = csr_src[base + o];
            float v = es[s * NCH + c] + edc;
            logit = v >= 0.f ? v : 0.2f * v;
        }
        float cm = logit;
#pragma unroll
        for (int off = 32; off; off >>= 1) cm = fmaxf(cm, __shfl_xor(cm, off));
        float nm = fmaxf(m, cm);
        float resc = __expf(m - nm);
        float ex = (o < len) ? __expf(logit - nm) : 0.f;
        float cs = ex;
#pragma unroll
        for (int off = 32; off; off >>= 1) cs += __shfl_xor(cs, off);
        den = den * resc + cs;
        acc *= resc;
        m = nm;
        int jj = 0;
        for (; jj + 4 <= len; jj += 4) {
            int s0 = __shfl(s, jj), s1 = __shfl(s, jj + 1);
            int s2 = __shfl(s, jj + 2), s3 = __shfl(s, jj + 3);
            float e0 = __shfl(ex, jj), e1 = __shfl(ex, jj + 1);
            float e2 = __shfl(ex, jj + 2), e3 = __shfl(ex, jj + 3);
            float h0 = hc[(size_t)s0 * 256];
            float h1 = hc[(size_t)s1 * 256];
            float h2 = hc[(size_t)s2 * 256];
            float h3 = hc[(size_t)s3 * 256];
            acc = fmaf(e0, h0, fmaf(e1, h1, fmaf(e2, h2, fmaf(e3, h3, acc))));
        }
        for (; jj < len; ++jj) {
            int sj = __shfl(s, jj);
            float ej = __shfl(ex, jj);
            acc = fmaf(ej, hc[(size_t)sj * 256], acc);
        }
    }
    float r = acc / (den + 1e-16f);
    out[(size_t)d * 256 + c * 64 + o] = SILU_OUT ? silu_f(r) : r;
}

// ---------- MLP layers 2+3 (64->32->1, all channels) + energy reduction ----------
// block = 32 nodes. thread (np=tid>>3 node, o8=tid&7 output-quad). W2 rows padded
// to 68 + (k>>2)^(o2>>2) swizzle -> conflict-free reads; t1 staged at stride 260.
__global__ __launch_bounds__(256) void mlp23_kernel(const float* __restrict__ t1g,
                                                    const float* __restrict__ W2,
                                                    const float* __restrict__ W3,
                                                    const int* __restrict__ bat,
                                                    float* __restrict__ out) {
    __shared__ float W2t[NCH * 32 * 68];  // [c][o2][swz k] padded
    __shared__ float t1l[32 * 260];       // [node][256] padded
    __shared__ float w3l[NCH * 32];
    const int tid = threadIdx.x;
    const int n0 = blockIdx.x * 32;
    const int np = tid >> 3;   // node 0..31
    const int o8 = tid & 7;    // output quad 0..7

    for (int i = tid; i < NCH * 2048; i += 256) {
        int cc = i >> 11, rem = i & 2047;
        int k = rem >> 5, o2 = rem & 31;
        W2t[cc * (32 * 68) + o2 * 68 + ((((k >> 2) ^ (o2 >> 2)) & 15) << 2 | (k & 3))] = W2[i];
    }
    for (int i = tid; i < 32 * 256; i += 256) {
        int nl = i >> 8, j = i & 255;
        t1l[nl * 260 + j] = t1g[(size_t)(n0 + nl) * 256 + j];
    }
    if (tid < NCH * 32) w3l[tid] = W3[tid];
    __syncthreads();

    float y = 0.f;
#pragma unroll
    for (int c = 0; c < NCH; ++c) {
        const float* ip = t1l + np * 260 + c * 64;
        const float* wp = W2t + c * (32 * 68) + (o8 * 4) * 68;
        float a0 = 0.f, a1 = 0.f, a2 = 0.f, a3 = 0.f;
#pragma unroll 4
        for (int kq = 0; kq < 16; ++kq) {
            int skq = ((kq ^ o8) & 15) << 2;
            float4 v = *(const float4*)(ip + (kq << 2));  // 8-lane broadcast
            float4 w0 = *(const float4*)(wp + skq);
            float4 w1 = *(const float4*)(wp + 68 + skq);
            float4 w2 = *(const float4*)(wp + 136 + skq);
            float4 w3 = *(const float4*)(wp + 204 + skq);
            a0 = fmaf(v.x, w0.x, fmaf(v.y, w0.y, fmaf(v.z, w0.z, fmaf(v.w, w0.w, a0))));
            a1 = fmaf(v.x, w1.x, fmaf(v.y, w1.y, fmaf(v.z, w1.z, fmaf(v.w, w1.w, a1))));
            a2 = fmaf(v.x, w2.x, fmaf(v.y, w2.y, fmaf(v.z, w2.z, fmaf(v.w, w2.w, a2))));
            a3 = fmaf(v.x, w3.x, fmaf(v.y, w3.y, fmaf(v.z, w3.z, fmaf(v.w, w3.w, a3))));
        }
        float4 w34 = *(const float4*)(w3l + c * 32 + o8 * 4);
        y += silu_f(a0) * w34.x + silu_f(a1) * w34.y + silu_f(a2) * w34.z + silu_f(a3) * w34.w;
    }
    // reduce over the 8 lanes of this node (xor -> all 8 lanes hold node sum)
#pragma unroll
    for (int off = 1; off < 8; off <<= 1) y += __shfl_xor(y, off);

    // wave w covers nodes w*8..w*8+7; gather node sums into lanes 0..7
    int l = tid & 63;
    int w = tid >> 6;
    float yn = __shfl(y, (l & 7) * 8);
    bool active = l < 8;
    int node = n0 + w * 8 + (l & 7);
    float val = yn * 0.025f;  // /sqrt(4)/20
    int b = bat[node];
    unsigned long long rem = __ballot(active);
    while (rem) {
        int lead = (int)__ffsll(rem) - 1;
        int bl = __shfl(b, lead);
        bool mine = active && (b == bl);
        float t = mine ? val : 0.f;
#pragma unroll
        for (int off = 1; off < 8; off <<= 1) t += __shfl_xor(t, off);
        if (l == lead) atomicAdd(out + bl, t);
        rem &= ~__ballot(mine);
    }
}

extern "C" void kernel_launch(void* const* d_in, const int* in_sizes, int n_in,
                              void* d_out, int out_size, void* d_ws, size_t ws_size,
                              hipStream_t stream) {
    const float* x     = (const float*)d_in[0];
    const int*   ei    = (const int*)d_in[1];
    const int*   bat   = (const int*)d_in[2];
    const float* gamma = (const float*)d_in[3];
    const float* beta  = (const float*)d_in[4];
    const float* Wc1   = (const float*)d_in[5];
    const float* as1   = (const float*)d_in[6];
    const float* ad1   = (const float*)d_in[7];
    const float* Wc2   = (const float*)d_in[8];
    const float* as2   = (const float*)d_in[9];
    const float* ad2   = (const float*)d_in[10];
    const float* Wn1   = (const float*)d_in[11];
    const float* Wn2   = (const float*)d_in[12];
    const float* Wout  = (const float*)d_in[13];
    float* out = (float*)d_out;

    // workspace layout (floats)
    float* A    = (float*)d_ws;            // conv outs
    float* B    = A + 10240000;            // proj output h [N,C,64]; t1g after gather2
    float* es   = B + 5120000;             // 80k
    float* ed   = es + 80000;              // 80k
    int* rowp   = (int*)(ed + 80000);      // 20001 (pad 20004)
    int* cnt    = rowp + 20004;            // 20000
    int* fillc  = cnt + 20000;             // 20000
    int* csr    = fillc + 20000;           // 400000
    int* bsum   = csr + 400000;            // 128
    int* boff   = bsum + 128;              // 128
    float* C1   = A;                       // conv1 out (silu'd) [N,C,64]
    float* C2   = A + 5120000;             // conv2 out (silu'd) [N,C,64]
    float* t1g  = B;                       // mlp hidden (B dead after gather2)

    dim3 blk(256);
    const int NB = (N_ATOMS + 255) / 256;   // 79
    const int NT = N_ATOMS / 32;            // 625 (exact)

    // ---- CSR build (graph is shared by both convs) ----
    fill_kernel<<<80, blk, 0, stream>>>((float*)cnt, 40000, 0.f);  // cnt + fillc (adjacent)
    hist_kernel<<<(N_EDGES + 255) / 256, blk, 0, stream>>>(ei, cnt, N_EDGES);
    scan_l1_kernel<<<NB, blk, 0, stream>>>(cnt, rowp, bsum, N_ATOMS);
    scan_l2_kernel<<<1, blk, 0, stream>>>(bsum, boff, rowp + N_ATOMS, NB, out);
    scan_l3_kernel<<<NB, blk, 0, stream>>>(rowp, boff, N_ATOMS);
    scatter_kernel<<<(N_EDGES + 255) / 256, blk, 0, stream>>>(ei, rowp, fillc, csr, N_EDGES);

    // ---- conv1 (LN fused into proj staging) ----
    proj_kernel<128, NCH * F_IN, true, true, false>
        <<<dim3(NT, NCH), blk, 0, stream>>>(x, gamma, beta, Wc1, as1, ad1, B, es, ed);
    gat_gather_kernel<true><<<N_ATOMS, blk, 0, stream>>>(rowp, csr, es, ed, B, C1);

    // ---- conv2 ----
    proj_kernel<64, 256, false, true, false>
        <<<dim3(NT, NCH), blk, 0, stream>>>(C1, gamma, beta, Wc2, as2, ad2, B, es, ed);
    gat_gather_kernel<true><<<N_ATOMS, blk, 0, stream>>>(rowp, csr, es, ed, B, C2);

    // ---- MLP: layer1 via proj structure (silu out), then 64->32->1 + energies ----
    proj_kernel<64, 256, false, false, true>
        <<<dim3(NT, NCH), blk, 0, stream>>>(C2, gamma, beta, Wn1, as1, ad1, t1g, es, ed);
    mlp23_kernel<<<NT, blk, 0, stream>>>(t1g, Wn2, Wout, bat, out);
}

// Round 13
// 280.714 us; speedup vs baseline: 1.1993x; 1.0557x over previous
//
#include <hip/hip_runtime.h>
#include <hip/hip_bf16.h>
#include <hip/hip_fp16.h>

// Problem constants (match reference)
#define N_ATOMS 20000
#define N_EDGES 400000
#define NCH 4
#define F_IN 128
#define S_OUT 32

// ---------- helpers ----------
__device__ __forceinline__ float silu_f(float v) { return v / (1.f + __expf(-v)); }

__device__ __forceinline__ int wave_iscan(int v, int l) {
#pragma unroll
    for (int off = 1; off < 64; off <<= 1) {
        int t = __shfl_up(v, off);
        if (l >= off) v += t;
    }
    return v;
}

// ---------- fill ----------
__global__ void fill_kernel(float* __restrict__ p, int n, float v) {
    int i = blockIdx.x * blockDim.x + threadIdx.x;
    int stride = gridDim.x * blockDim.x;
    for (; i < n; i += stride) p[i] = v;
}

// ---------- CSR build: histogram -> hierarchical scan -> scatter ----------
__global__ void hist_kernel(const int* __restrict__ ei, int* __restrict__ cnt, int E) {
    int e = blockIdx.x * 256 + threadIdx.x;
    if (e < E) atomicAdd(&cnt[ei[E + e]], 1);
}

__global__ __launch_bounds__(256) void scan_l1_kernel(const int* __restrict__ cnt,
                                                      int* __restrict__ rowp,
                                                      int* __restrict__ bsum, int n) {
    int i = blockIdx.x * 256 + threadIdx.x;
    int l = threadIdx.x & 63, w = threadIdx.x >> 6;
    int v = (i < n) ? cnt[i] : 0;
    int incl = wave_iscan(v, l);
    __shared__ int wsum[4];
    if (l == 63) wsum[w] = incl;
    __syncthreads();
    int add = 0;
#pragma unroll
    for (int j = 0; j < 4; ++j) add += (j < w) ? wsum[j] : 0;
    if (i < n) rowp[i] = add + incl - v;
    if (threadIdx.x == 255) bsum[blockIdx.x] = add + incl;
}

__global__ __launch_bounds__(256) void scan_l2_kernel(const int* __restrict__ bsum,
                                                      int* __restrict__ boff,
                                                      int* __restrict__ rowp_n, int nb,
                                                      float* __restrict__ out_zero) {
    int i = threadIdx.x;
    if (i < S_OUT) out_zero[i] = 0.f;  // fused energies zero-init
    int l = i & 63, w = i >> 6;
    int v = (i < nb) ? bsum[i] : 0;
    int incl = wave_iscan(v, l);
    __shared__ int wsum[4];
    if (l == 63) wsum[w] = incl;
    __syncthreads();
    int add = 0;
#pragma unroll
    for (int j = 0; j < 4; ++j) add += (j < w) ? wsum[j] : 0;
    if (i < nb) boff[i] = add + incl - v;
    if (i == nb - 1) *rowp_n = add + incl;
}

__global__ __launch_bounds__(256) void scan_l3_kernel(int* __restrict__ rowp,
                                                      const int* __restrict__ boff, int n) {
    int i = blockIdx.x * 256 + threadIdx.x;
    if (i < n) rowp[i] += boff[blockIdx.x];
}

__global__ void scatter_kernel(const int* __restrict__ ei, const int* __restrict__ rowp,
                               int* __restrict__ fill, int* __restrict__ csr_src, int E) {
    int e = blockIdx.x * 256 + threadIdx.x;
    if (e < E) {
        int d = ei[E + e];
        int pos = rowp[d] + atomicAdd(&fill[d], 1);
        csr_src[pos] = ei[e];
    }
}

// ---------- projection: 2-node x 4-output register tile ----------
// block = 32 nodes, c = blockIdx.y. thread (np=t>>4, oq=t&15) owns acc[2][4].
// OUT_HALF: h consumed only by the gather -> store fp16 (halves gather traffic).
template <int FIN, int IN_STRIDE, bool LN, bool ATT, bool SILU_OUT, bool OUT_HALF>
__global__ __launch_bounds__(256) void proj_kernel(const float* __restrict__ in,
                                                   const float* __restrict__ gamma,
                                                   const float* __restrict__ beta,
                                                   const float* __restrict__ W,
                                                   const float* __restrict__ a_src,
                                                   const float* __restrict__ a_dst,
                                                   void* __restrict__ outv,
                                                   float* __restrict__ es,
                                                   float* __restrict__ ed) {
    constexpr int KQ = FIN / 4;
    constexpr int KQM = KQ - 1;
    constexpr int WS = FIN + 4;       // padded stride (16B-aligned, bank-spread)
    __shared__ float Wt[64 * WS];     // [o][swizzled k], padded
    __shared__ float inl[32 * WS];    // [node][k], padded
    const int tid = threadIdx.x;
    const int c = blockIdx.y;
    const int n0 = blockIdx.x * 32;
    const int np = tid >> 4;          // node pair 0..15
    const int oq = tid & 15;          // output quad 0..15

    const float* __restrict__ Wc = W + c * (FIN * 64);
    for (int i = tid; i < FIN * 64; i += 256) {
        int k = i >> 6, oo = i & 63;
        Wt[oo * WS + (((((k >> 2) ^ (oo >> 2)) & KQM) << 2) | (k & 3))] = Wc[i];
    }
    for (int i = tid; i < 32 * FIN; i += 256) {
        int nl = i / FIN, k = i & (FIN - 1);
        inl[nl * WS + k] = in[(size_t)(n0 + nl) * IN_STRIDE + c * FIN + k];
    }
    __syncthreads();

    if (LN) {  // in-place LayerNorm per 128-row; wave w owns rows 8w..8w+7
        int l = tid & 63, w = tid >> 6;
        float gl0 = gamma[l], gl1 = gamma[l + 64];
        float bl0 = beta[l], bl1 = beta[l + 64];
#pragma unroll
        for (int r = 0; r < 8; ++r) {
            int row = w * 8 + r;
            float v0 = inl[row * WS + l], v1 = inl[row * WS + l + 64];
            float s = v0 + v1, sq = v0 * v0 + v1 * v1;
#pragma unroll
            for (int off = 32; off; off >>= 1) {
                s += __shfl_xor(s, off);
                sq += __shfl_xor(sq, off);
            }
            float mu = s * (1.f / 128.f);
            float rs = rsqrtf(sq * (1.f / 128.f) - mu * mu + 1e-5f);
            inl[row * WS + l]      = (v0 - mu) * rs * gl0 + bl0;
            inl[row * WS + l + 64] = (v1 - mu) * rs * gl1 + bl1;
        }
        __syncthreads();
    }

    float acc[2][4];
#pragma unroll
    for (int i = 0; i < 2; ++i)
#pragma unroll
        for (int j = 0; j < 4; ++j) acc[i][j] = 0.f;

    const float* inp0 = inl + (np * 2) * WS;
    const float* inp1 = inl + (np * 2 + 1) * WS;
    const float* wp = Wt + (oq * 4) * WS;

#pragma unroll 2
    for (int kq = 0; kq < KQ; ++kq) {
        int skq = ((kq ^ oq) & KQM) << 2;
        float4 v0 = *(const float4*)(inp0 + (kq << 2));
        float4 v1 = *(const float4*)(inp1 + (kq << 2));
        float4 w0 = *(const float4*)(wp + skq);
        float4 w1 = *(const float4*)(wp + WS + skq);
        float4 w2 = *(const float4*)(wp + 2 * WS + skq);
        float4 w3 = *(const float4*)(wp + 3 * WS + skq);
        acc[0][0] = fmaf(v0.x, w0.x, fmaf(v0.y, w0.y, fmaf(v0.z, w0.z, fmaf(v0.w, w0.w, acc[0][0]))));
        acc[0][1] = fmaf(v0.x, w1.x, fmaf(v0.y, w1.y, fmaf(v0.z, w1.z, fmaf(v0.w, w1.w, acc[0][1]))));
        acc[0][2] = fmaf(v0.x, w2.x, fmaf(v0.y, w2.y, fmaf(v0.z, w2.z, fmaf(v0.w, w2.w, acc[0][2]))));
        acc[0][3] = fmaf(v0.x, w3.x, fmaf(v0.y, w3.y, fmaf(v0.z, w3.z, fmaf(v0.w, w3.w, acc[0][3]))));
        acc[1][0] = fmaf(v1.x, w0.x, fmaf(v1.y, w0.y, fmaf(v1.z, w0.z, fmaf(v1.w, w0.w, acc[1][0]))));
        acc[1][1] = fmaf(v1.x, w1.x, fmaf(v1.y, w1.y, fmaf(v1.z, w1.z, fmaf(v1.w, w1.w, acc[1][1]))));
        acc[1][2] = fmaf(v1.x, w2.x, fmaf(v1.y, w2.y, fmaf(v1.z, w2.z, fmaf(v1.w, w2.w, acc[1][2]))));
        acc[1][3] = fmaf(v1.x, w3.x, fmaf(v1.y, w3.y, fmaf(v1.z, w3.z, fmaf(v1.w, w3.w, acc[1][3]))));
    }

#pragma unroll
    for (int i = 0; i < 2; ++i) {
        int node = n0 + np * 2 + i;
        float o0 = acc[i][0], o1 = acc[i][1], o2 = acc[i][2], o3 = acc[i][3];
        if (SILU_OUT) { o0 = silu_f(o0); o1 = silu_f(o1); o2 = silu_f(o2); o3 = silu_f(o3); }
        if (OUT_HALF) {
            __half* outh = (__half*)outv;
            float2 st;
            __half2* sp = (__half2*)&st;
            sp[0] = __floats2half2_rn(o0, o1);
            sp[1] = __floats2half2_rn(o2, o3);
            *(float2*)(outh + (size_t)node * 256 + c * 64 + oq * 4) = st;
        } else {
            *(float4*)((float*)outv + (size_t)node * 256 + c * 64 + oq * 4) =
                make_float4(o0, o1, o2, o3);
        }
        if (ATT) {
            float4 av4 = *(const float4*)(a_src + c * 64 + oq * 4);
            float4 bv4 = *(const float4*)(a_dst + c * 64 + oq * 4);
            float ps = acc[i][0] * av4.x + acc[i][1] * av4.y + acc[i][2] * av4.z + acc[i][3] * av4.w;
            float pd = acc[i][0] * bv4.x + acc[i][1] * bv4.y + acc[i][2] * bv4.z + acc[i][3] * bv4.w;
#pragma unroll
            for (int off = 1; off < 16; off <<= 1) {
                ps += __shfl_xor(ps, off);
                pd += __shfl_xor(pd, off);
            }
            if (oq == 0) { es[node * NCH + c] = ps; ed[node * NCH + c] = pd; }
        }
    }
}

// ---------- fused GAT aggregation: wave-autonomous, LDS-free, fp16 h ----------
template <bool SILU_OUT>
__global__ __launch_bounds__(256) void gat_gather_kernel(const int* __restrict__ rowp,
                                                         const int* __restrict__ csr_src,
                                                         const float* __restrict__ es,
                                                         const float* __restrict__ ed,
                                                         const __half* __restrict__ h,
                                                         float* __restrict__ out) {
    int d = blockIdx.x;
    int c = threadIdx.x >> 6, o = threadIdx.x & 63;
    int r0 = rowp[d], r1 = rowp[d + 1];
    float edc = ed[d * NCH + c];
    float m = -1e30f, den = 0.f, acc = 0.f;
    const __half* __restrict__ hc = h + c * 64 + o;
    for (int base = r0; base < r1; base += 64) {
        int len = min(64, r1 - base);
        float logit = -1e30f;
        int s = 0;
        if (o < len) {
            s = csr_src[base + o];
            float v = es[s * NCH + c] + edc;
            logit = v >= 0.f ? v : 0.2f * v;
        }
        float cm = logit;
#pragma unroll
        for (int off = 32; off; off >>= 1) cm = fmaxf(cm, __shfl_xor(cm, off));
        float nm = fmaxf(m, cm);
        float resc = __expf(m - nm);
        float ex = (o < len) ? __expf(logit - nm) : 0.f;
        float cs = ex;
#pragma unroll
        for (int off = 32; off; off >>= 1) cs += __shfl_xor(cs, off);
        den = den * resc + cs;
        acc *= resc;
        m = nm;
        int jj = 0;
        for (; jj + 4 <= len; jj += 4) {
            int s0 = __shfl(s, jj), s1 = __shfl(s, jj + 1);
            int s2 = __shfl(s, jj + 2), s3 = __shfl(s, jj + 3);
            float e0 = __shfl(ex, jj), e1 = __shfl(ex, jj + 1);
            float e2 = __shfl(ex, jj + 2), e3 = __shfl(ex, jj + 3);
            float h0 = __half2float(hc[(size_t)s0 * 256]);
            float h1 = __half2float(hc[(size_t)s1 * 256]);
            float h2 = __half2float(hc[(size_t)s2 * 256]);
            float h3 = __half2float(hc[(size_t)s3 * 256]);
            acc = fmaf(e0, h0, fmaf(e1, h1, fmaf(e2, h2, fmaf(e3, h3, acc))));
        }
        for (; jj < len; ++jj) {
            int sj = __shfl(s, jj);
            float ej = __shfl(ex, jj);
            acc = fmaf(ej, __half2float(hc[(size_t)sj * 256]), acc);
        }
    }
    float r = acc / (den + 1e-16f);
    out[(size_t)d * 256 + c * 64 + o] = SILU_OUT ? silu_f(r) : r;
}

// ---------- MLP layers 2+3 (64->32->1, all channels) + energy reduction ----------
__global__ __launch_bounds__(256) void mlp23_kernel(const float* __restrict__ t1g,
                                                    const float* __restrict__ W2,
                                                    const float* __restrict__ W3,
                                                    const int* __restrict__ bat,
                                                    float* __restrict__ out) {
    __shared__ float W2t[NCH * 32 * 68];  // [c][o2][swz k] padded
    __shared__ float t1l[32 * 260];       // [node][256] padded
    __shared__ float w3l[NCH * 32];
    const int tid = threadIdx.x;
    const int n0 = blockIdx.x * 32;
    const int np = tid >> 3;   // node 0..31
    const int o8 = tid & 7;    // output quad 0..7

    for (int i = tid; i < NCH * 2048; i += 256) {
        int cc = i >> 11, rem = i & 2047;
        int k = rem >> 5, o2 = rem & 31;
        W2t[cc * (32 * 68) + o2 * 68 + ((((k >> 2) ^ (o2 >> 2)) & 15) << 2 | (k & 3))] = W2[i];
    }
    for (int i = tid; i < 32 * 256; i += 256) {
        int nl = i >> 8, j = i & 255;
        t1l[nl * 260 + j] = t1g[(size_t)(n0 + nl) * 256 + j];
    }
    if (tid < NCH * 32) w3l[tid] = W3[tid];
    __syncthreads();

    float y = 0.f;
#pragma unroll
    for (int c = 0; c < NCH; ++c) {
        const float* ip = t1l + np * 260 + c * 64;
        const float* wp = W2t + c * (32 * 68) + (o8 * 4) * 68;
        float a0 = 0.f, a1 = 0.f, a2 = 0.f, a3 = 0.f;
#pragma unroll 4
        for (int kq = 0; kq < 16; ++kq) {
            int skq = ((kq ^ o8) & 15) << 2;
            float4 v = *(const float4*)(ip + (kq << 2));  // 8-lane broadcast
            float4 w0 = *(const float4*)(wp + skq);
            float4 w1 = *(const float4*)(wp + 68 + skq);
            float4 w2 = *(const float4*)(wp + 136 + skq);
            float4 w3 = *(const float4*)(wp + 204 + skq);
            a0 = fmaf(v.x, w0.x, fmaf(v.y, w0.y, fmaf(v.z, w0.z, fmaf(v.w, w0.w, a0))));
            a1 = fmaf(v.x, w1.x, fmaf(v.y, w1.y, fmaf(v.z, w1.z, fmaf(v.w, w1.w, a1))));
            a2 = fmaf(v.x, w2.x, fmaf(v.y, w2.y, fmaf(v.z, w2.z, fmaf(v.w, w2.w, a2))));
            a3 = fmaf(v.x, w3.x, fmaf(v.y, w3.y, fmaf(v.z, w3.z, fmaf(v.w, w3.w, a3))));
        }
        float4 w34 = *(const float4*)(w3l + c * 32 + o8 * 4);
        y += silu_f(a0) * w34.x + silu_f(a1) * w34.y + silu_f(a2) * w34.z + silu_f(a3) * w34.w;
    }
#pragma unroll
    for (int off = 1; off < 8; off <<= 1) y += __shfl_xor(y, off);

    int l = tid & 63;
    int w = tid >> 6;
    float yn = __shfl(y, (l & 7) * 8);
    bool active = l < 8;
    int node = n0 + w * 8 + (l & 7);
    float val = yn * 0.025f;  // /sqrt(4)/20
    int b = bat[node];
    unsigned long long rem = __ballot(active);
    while (rem) {
        int lead = (int)__ffsll(rem) - 1;
        int bl = __shfl(b, lead);
        bool mine = active && (b == bl);
        float t = mine ? val : 0.f;
#pragma unroll
        for (int off = 1; off < 8; off <<= 1) t += __shfl_xor(t, off);
        if (l == lead) atomicAdd(out + bl, t);
        rem &= ~__ballot(mine);
    }
}

extern "C" void kernel_launch(void* const* d_in, const int* in_sizes, int n_in,
                              void* d_out, int out_size, void* d_ws, size_t ws_size,
                              hipStream_t stream) {
    const float* x     = (const float*)d_in[0];
    const int*   ei    = (const int*)d_in[1];
    const int*   bat   = (const int*)d_in[2];
    const float* gamma = (const float*)d_in[3];
    const float* beta  = (const float*)d_in[4];
    const float* Wc1   = (const float*)d_in[5];
    const float* as1   = (const float*)d_in[6];
    const float* ad1   = (const float*)d_in[7];
    const float* Wc2   = (const float*)d_in[8];
    const float* as2   = (const float*)d_in[9];
    const float* ad2   = (const float*)d_in[10];
    const float* Wn1   = (const float*)d_in[11];
    const float* Wn2   = (const float*)d_in[12];
    const float* Wout  = (const float*)d_in[13];
    float* out = (float*)d_out;

    // workspace layout (floats)
    float* A    = (float*)d_ws;            // conv outs
    float* B    = A + 10240000;            // h buffer: [N][256] __half (2.56M floats used)
    float* es   = B + 5120000;             // 80k
    float* ed   = es + 80000;              // 80k
    int* rowp   = (int*)(ed + 80000);      // 20001 (pad 20004)
    int* cnt    = rowp + 20004;            // 20000
    int* fillc  = cnt + 20000;             // 20000
    int* csr    = fillc + 20000;           // 400000
    int* bsum   = csr + 400000;            // 128
    int* boff   = bsum + 128;              // 128
    float* C1   = A;                       // conv1 out (silu'd) [N,C,64] f32
    float* C2   = A + 5120000;             // conv2 out (silu'd) [N,C,64] f32
    __half* Bh  = (__half*)B;              // fp16 h for gathers
    float* t1g  = B;                       // mlp hidden f32 (B dead after gather2)

    dim3 blk(256);
    const int NB = (N_ATOMS + 255) / 256;   // 79
    const int NT = N_ATOMS / 32;            // 625 (exact)

    // ---- CSR build (graph is shared by both convs) ----
    fill_kernel<<<80, blk, 0, stream>>>((float*)cnt, 40000, 0.f);  // cnt + fillc (adjacent)
    hist_kernel<<<(N_EDGES + 255) / 256, blk, 0, stream>>>(ei, cnt, N_EDGES);
    scan_l1_kernel<<<NB, blk, 0, stream>>>(cnt, rowp, bsum, N_ATOMS);
    scan_l2_kernel<<<1, blk, 0, stream>>>(bsum, boff, rowp + N_ATOMS, NB, out);
    scan_l3_kernel<<<NB, blk, 0, stream>>>(rowp, boff, N_ATOMS);
    scatter_kernel<<<(N_EDGES + 255) / 256, blk, 0, stream>>>(ei, rowp, fillc, csr, N_EDGES);

    // ---- conv1 (LN fused into proj staging; h stored fp16) ----
    proj_kernel<128, NCH * F_IN, true, true, false, true>
        <<<dim3(NT, NCH), blk, 0, stream>>>(x, gamma, beta, Wc1, as1, ad1, Bh, es, ed);
    gat_gather_kernel<true><<<N_ATOMS, blk, 0, stream>>>(rowp, csr, es, ed, Bh, C1);

    // ---- conv2 ----
    proj_kernel<64, 256, false, true, false, true>
        <<<dim3(NT, NCH), blk, 0, stream>>>(C1, gamma, beta, Wc2, as2, ad2, Bh, es, ed);
    gat_gather_kernel<true><<<N_ATOMS, blk, 0, stream>>>(rowp, csr, es, ed, Bh, C2);

    // ---- MLP: layer1 via proj structure (silu out, f32), then 64->32->1 + energies ----
    proj_kernel<64, 256, false, false, true, false>
        <<<dim3(NT, NCH), blk, 0, stream>>>(C2, gamma, beta, Wn1, as1, ad1, t1g, es, ed);
    mlp23_kernel<<<NT, blk, 0, stream>>>(t1g, Wn2, Wout, bat, out);
}